// Round 1
// baseline (6301.431 us; speedup 1.0000x reference)
//
#include <hip/hip_runtime.h>
#include <cstddef>

// Problem dims
#define NR 4096      // batch
#define CDIM 512     // concepts
#define HDIM 128     // hidden
#define TSTEPS 64
#define DDIM 20
#define KTOP 10

// ---------------------------------------------------------------------------
// Generic fp32 tiled GEMM: C[M,N] = A[M,K] @ op(B) (+bias)(+leaky_relu)
// flags: 1 = B is [N,K] (compute A@B^T), else B is [K,N]; 2 = add bias[n];
// 4 = leaky_relu(0.01)
// Grid: (N/64, M/64, nz). Two arg-sets so dependent GEMM pairs share a launch.
// ---------------------------------------------------------------------------
struct GemmArgs {
    const float* A; const float* B; const float* bias; float* C;
    int N, K, flags;
};

__global__ __launch_bounds__(256) void gemm_multi(GemmArgs g0, GemmArgs g1)
{
    GemmArgs g = (blockIdx.z == 0) ? g0 : g1;
    const int tid = threadIdx.x;
    const int bm = blockIdx.y << 6, bn = blockIdx.x << 6;
    __shared__ float As[32][68];   // [k][m], 68 keeps float4 rows 16B-aligned
    __shared__ float Bs[32][68];   // [k][n]
    const int tx = tid & 15, ty = tid >> 4;
    const int lc = tid & 31, lr = tid >> 5;
    const int ln = tid & 63, lk = tid >> 6;
    const int K = g.K, N = g.N;
    float acc[4][4] = {};
    for (int k0 = 0; k0 < K; k0 += 32) {
        #pragma unroll
        for (int i = 0; i < 8; i++) {
            int row = lr + (i << 3);
            int k = k0 + lc;
            As[lc][row] = (k < K) ? g.A[(size_t)(bm + row) * K + k] : 0.f;
        }
        if (g.flags & 1) {
            #pragma unroll
            for (int i = 0; i < 8; i++) {
                int row = lr + (i << 3);
                int k = k0 + lc;
                Bs[lc][row] = (k < K) ? g.B[(size_t)(bn + row) * K + k] : 0.f;
            }
        } else {
            #pragma unroll
            for (int i = 0; i < 8; i++) {
                int kk = lk + (i << 2);
                int k = k0 + kk;
                Bs[kk][ln] = (k < K) ? g.B[(size_t)k * N + bn + ln] : 0.f;
            }
        }
        __syncthreads();
        #pragma unroll
        for (int kk = 0; kk < 32; kk++) {
            float a[4], b[4];
            #pragma unroll
            for (int i = 0; i < 4; i++) a[i] = As[kk][(ty << 2) + i];
            #pragma unroll
            for (int j = 0; j < 4; j++) b[j] = Bs[kk][(tx << 2) + j];
            #pragma unroll
            for (int i = 0; i < 4; i++)
                #pragma unroll
                for (int j = 0; j < 4; j++)
                    acc[i][j] += a[i] * b[j];
        }
        __syncthreads();
    }
    #pragma unroll
    for (int i = 0; i < 4; i++) {
        int m = bm + (ty << 2) + i;
        #pragma unroll
        for (int j = 0; j < 4; j++) {
            int n = bn + (tx << 2) + j;
            float v = acc[i][j];
            if (g.flags & 2) v += g.bias[n];
            if (g.flags & 4) v = v > 0.f ? v : 0.01f * v;
            g.C[(size_t)m * N + n] = v;
        }
    }
}

// x [N, D*T] -> seq [T, N, D]: seq[t,n,d] = x[n, d*T + t]
__global__ void seq_transpose(const float* __restrict__ x, float* __restrict__ seq)
{
    int idx = blockIdx.x * 256 + threadIdx.x;  // T*N*D = 5,242,880
    int d = idx % DDIM;
    int r = idx / DDIM;
    int n = r & (NR - 1);
    int t = r >> 12;
    seq[idx] = x[(size_t)n * (DDIM * TSTEPS) + d * TSTEPS + t];
}

// GRU elementwise update (torch gate order r,z,n)
__global__ void gru_update(float* __restrict__ h, const float* __restrict__ gx,
                           const float* __restrict__ gh, const float* __restrict__ bih,
                           const float* __restrict__ bhh)
{
    int idx = blockIdx.x * 256 + threadIdx.x;  // NR*HDIM
    int n = idx >> 7, j = idx & 127;
    const float* gxp = gx + (size_t)n * 384;
    const float* ghp = gh + (size_t)n * 384;
    float r = 1.f / (1.f + expf(-(gxp[j] + bih[j] + ghp[j] + bhh[j])));
    float z = 1.f / (1.f + expf(-(gxp[j + 128] + bih[j + 128] + ghp[j + 128] + bhh[j + 128])));
    float nc = tanhf(gxp[j + 256] + bih[j + 256] + r * (ghp[j + 256] + bhh[j + 256]));
    h[idx] = (1.f - z) * nc + z * h[idx];
}

// den[c] = sum_n cm[n,c]*mv[n]; grid 8 blocks x 256 thr, 64 cols per block
__global__ void den_kernel(const float* __restrict__ cm, const float* __restrict__ mv,
                           float* __restrict__ den)
{
    int c = blockIdx.x * 64 + (threadIdx.x & 63);
    int rg = threadIdx.x >> 6;  // 0..3
    float acc = 0.f;
    for (int n = rg; n < NR; n += 4) acc += cm[(size_t)n * CDIM + c] * mv[n];
    __shared__ float red[4][64];
    red[rg][threadIdx.x & 63] = acc;
    __syncthreads();
    if (rg == 0)
        den[c] = red[0][threadIdx.x] + red[1][threadIdx.x] + red[2][threadIdx.x] + red[3][threadIdx.x];
}

// s2cT[c,n] = cm[n,c]*mv[n] / (den[c]*cm[n,c] + 1)
__global__ void s2ct_kernel(const float* __restrict__ cm, const float* __restrict__ mv,
                            const float* __restrict__ den, float* __restrict__ s2cT)
{
    int idx = blockIdx.x * 256 + threadIdx.x;  // CDIM*NR
    int c = idx >> 12, n = idx & (NR - 1);
    float m = cm[(size_t)n * CDIM + c];
    s2cT[idx] = (m * mv[n]) / (den[c] * m + 1.f);
}

// per-row L2 norm of a [rows, H=128] matrix; block = 64 (one wave)
__global__ void row_norm(const float* __restrict__ a, float* __restrict__ out)
{
    int r = blockIdx.x;
    float acc = 0.f;
    for (int h = threadIdx.x; h < HDIM; h += 64) {
        float v = a[(size_t)r * HDIM + h];
        acc += v * v;
    }
    for (int o = 32; o > 0; o >>= 1) acc += __shfl_down(acc, o);
    if (threadIdx.x == 0) out[r] = sqrtf(acc);
}

// validity flag: (sum_h a[r,h]) != 0 -> 1.0 else 0.0
__global__ void row_nonzero(const float* __restrict__ a, float* __restrict__ out)
{
    int r = blockIdx.x;
    float acc = 0.f;
    for (int h = threadIdx.x; h < HDIM; h += 64) acc += a[(size_t)r * HDIM + h];
    for (int o = 32; o > 0; o >>= 1) acc += __shfl_down(acc, o);
    if (threadIdx.x == 0) out[r] = (acc != 0.f) ? 1.f : 0.f;
}

// In-place per-row: optional cosine normalize (rn[row]*cn[col]), optional
// -1e9 mask where vmask[col]==0, softmax(max-subtracted), optional *vmask.
__global__ __launch_bounds__(256) void cos_softmax_row(float* __restrict__ data, int N,
        const float* __restrict__ rn, const float* __restrict__ cn,
        const float* __restrict__ vmask)
{
    int row = blockIdx.x;
    float* d = data + (size_t)row * N;
    int tid = threadIdx.x;
    __shared__ float red[256];
    float rnv = rn ? rn[row] : 0.f;
    float mx = -INFINITY;
    for (int j = tid; j < N; j += 256) {
        float v = d[j];
        if (cn) v = v / fmaxf(rnv * cn[j], 1e-12f);
        if (vmask && vmask[j] == 0.f) v = -1e9f;
        d[j] = v;
        mx = fmaxf(mx, v);
    }
    red[tid] = mx; __syncthreads();
    for (int s = 128; s > 0; s >>= 1) {
        if (tid < s) red[tid] = fmaxf(red[tid], red[tid + s]);
        __syncthreads();
    }
    float M = red[0]; __syncthreads();
    float sum = 0.f;
    for (int j = tid; j < N; j += 256) {
        float e = expf(d[j] - M);
        d[j] = e;
        sum += e;
    }
    red[tid] = sum; __syncthreads();
    for (int s = 128; s > 0; s >>= 1) {
        if (tid < s) red[tid] += red[tid + s];
        __syncthreads();
    }
    float inv = 1.f / red[0];
    for (int j = tid; j < N; j += 256) {
        float v = d[j] * inv;
        if (vmask) v *= vmask[j];
        d[j] = v;
    }
}

// hs2c: normalize by norms, capture diagonal, zero diagonal
__global__ void hs2c_norm(float* __restrict__ S, const float* __restrict__ hn,
                          float* __restrict__ diag)
{
    int idx = blockIdx.x * 256 + threadIdx.x;  // NR*NR
    int i = idx >> 12, j = idx & (NR - 1);
    float v = S[idx] / fmaxf(hn[i] * hn[j], 1e-12f);
    if (i == j) { diag[i] = v; v = 0.f; }
    S[idx] = v;
}

// top-10 per row of S [NR, NR]; block 256, 16 elems/thread, 10 argmax passes
__global__ __launch_bounds__(256) void topk_kernel(const float* __restrict__ S,
        float* __restrict__ vals, int* __restrict__ idxs)
{
    int row = blockIdx.x;
    const float* d = S + (size_t)row * NR;
    int tid = threadIdx.x;
    float lv[16]; int li[16];
    #pragma unroll
    for (int i = 0; i < 16; i++) {
        int j = tid + i * 256;
        lv[i] = d[j];
        li[i] = j;
    }
    __shared__ float sv[256];
    __shared__ int si[256];
    for (int k = 0; k < KTOP; k++) {
        float bv = -INFINITY; int bi = 0x7fffffff;
        #pragma unroll
        for (int i = 0; i < 16; i++) {
            if (lv[i] > bv || (lv[i] == bv && li[i] < bi)) { bv = lv[i]; bi = li[i]; }
        }
        sv[tid] = bv; si[tid] = bi;
        __syncthreads();
        for (int s = 128; s > 0; s >>= 1) {
            if (tid < s) {
                if (sv[tid + s] > sv[tid] || (sv[tid + s] == sv[tid] && si[tid + s] < si[tid])) {
                    sv[tid] = sv[tid + s]; si[tid] = si[tid + s];
                }
            }
            __syncthreads();
        }
        if (tid == 0) { vals[row * KTOP + k] = sv[0]; idxs[row * KTOP + k] = si[0]; }
        int w = si[0];
        if ((w & 255) == tid) lv[w >> 8] = -INFINITY;
        __syncthreads();
    }
}

__global__ void colsum_scatter(const float* __restrict__ vals, const int* __restrict__ idxs,
                               float* __restrict__ colsum)
{
    int idx = blockIdx.x * 256 + threadIdx.x;
    if (idx < NR * KTOP) atomicAdd(&colsum[idxs[idx]], vals[idx]);
}

// hidden_h[j,:] += val * h_shared[i,:]  for each top-k entry (i -> j)
__global__ void hh_scatter(const float* __restrict__ vals, const int* __restrict__ idxs,
                           const float* __restrict__ hsh, float* __restrict__ hh)
{
    int p = blockIdx.x;           // NR*KTOP blocks
    int j = idxs[p];
    float v = vals[p];
    int i = p / KTOP;
    atomicAdd(&hh[(size_t)j * HDIM + threadIdx.x], v * hsh[(size_t)i * HDIM + threadIdx.x]);
}

// diagonal term: if colsum[j] != 0: hidden_h[j,:] += diag[j]*h_shared[j,:]
__global__ void hh_diag(const float* __restrict__ colsum, const float* __restrict__ diag,
                        const float* __restrict__ hsh, float* __restrict__ hh)
{
    int idx = blockIdx.x * 256 + threadIdx.x;  // NR*HDIM
    int j = idx >> 7;
    if (colsum[j] != 0.f) hh[idx] += diag[j] * hsh[idx];
}

__global__ void sub2_kernel(const float* __restrict__ a, const float* __restrict__ b,
                            float* __restrict__ o)
{
    int i = blockIdx.x * 256 + threadIdx.x;
    o[i] = a[i] - b[i];
}

__global__ void sub3_kernel(const float* __restrict__ a, const float* __restrict__ b,
                            const float* __restrict__ c, float* __restrict__ o)
{
    int i = blockIdx.x * 256 + threadIdx.x;
    o[i] = a[i] - b[i] - c[i];
}

// out[n] = sum_h (ps+hs+indi)[n,h]*w[h] + b[0]
__global__ void head_kernel(const float* __restrict__ ps, const float* __restrict__ hs,
                            const float* __restrict__ indi, const float* __restrict__ w,
                            const float* __restrict__ b, float* __restrict__ out)
{
    int n = blockIdx.x;
    int t = threadIdx.x;  // 64
    float acc = 0.f;
    for (int h = t; h < HDIM; h += 64) {
        size_t k = (size_t)n * HDIM + h;
        acc += (ps[k] + hs[k] + indi[k]) * w[h];
    }
    for (int o = 32; o > 0; o >>= 1) acc += __shfl_down(acc, o);
    if (t == 0) out[n] = acc + b[0];
}

static inline void launch_gemm(hipStream_t s, const float* A, const float* B,
                               const float* bias, float* C, int M, int N, int K, int flags)
{
    GemmArgs g{A, B, bias, C, N, K, flags};
    gemm_multi<<<dim3(N / 64, M / 64, 1), 256, 0, s>>>(g, g);
}

extern "C" void kernel_launch(void* const* d_in, const int* in_sizes, int n_in,
                              void* d_out, int out_size, void* d_ws, size_t ws_size,
                              hipStream_t stream)
{
    (void)in_sizes; (void)n_in; (void)out_size; (void)ws_size;
    const float* x    = (const float*)d_in[0];
    const float* cm   = (const float*)d_in[1];
    const float* mv   = (const float*)d_in[2];
    const float* wih0 = (const float*)d_in[3];
    const float* whh0 = (const float*)d_in[4];
    const float* bih0 = (const float*)d_in[5];
    const float* bhh0 = (const float*)d_in[6];
    const float* wih1 = (const float*)d_in[7];
    const float* whh1 = (const float*)d_in[8];
    const float* bih1 = (const float*)d_in[9];
    const float* bhh1 = (const float*)d_in[10];
    const float* w_ps = (const float*)d_in[11];
    const float* b_ps = (const float*)d_in[12];
    const float* w_hs = (const float*)d_in[13];
    const float* b_hs = (const float*)d_in[14];
    const float* w_ps_fore = (const float*)d_in[15];
    const float* b_ps_fore = (const float*)d_in[16];
    const float* w_hs_fore = (const float*)d_in[17];
    const float* b_hs_fore = (const float*)d_in[18];
    const float* w_ps_back = (const float*)d_in[19];
    const float* b_ps_back = (const float*)d_in[20];
    const float* w_hs_back = (const float*)d_in[21];
    const float* b_hs_back = (const float*)d_in[22];
    const float* w_indi = (const float*)d_in[23];
    const float* b_indi = (const float*)d_in[24];
    const float* w_out  = (const float*)d_in[25];
    const float* b_out  = (const float*)d_in[26];
    float* out = (float*)d_out;

    // ---- workspace layout (floats) ----
    float* ws = (float*)d_ws;
    float* BIG = ws;                         // 16,777,216 (hs2c / hc2s; overlaid below)
    float* h0 = ws + 16777216;               // 524288
    float* h1 = h0 + 524288;                 // 524288 (= x_hidden)
    float* den = h1 + 524288;                // 512
    float* v1 = den + 512;                   // 512
    float* hidden = v1 + 512;                // 65536
    float* hidden2 = hidden + 65536;         // 65536
    float* xnorm = hidden2 + 65536;          // 4096
    float* h2n = xnorm + 4096;               // 512
    float* p0 = h2n + 512;                   // 524288
    float* p_shared = p0 + 524288;
    float* p_back = p_shared + 524288;
    float* out_ps = p_back + 524288;
    float* h_shared = out_ps + 524288;
    float* hn = h_shared + 524288;           // 4096
    float* diagv = hn + 4096;                // 4096
    float* colsum = diagv + 4096;            // 4096
    float* tvals = colsum + 4096;            // 40960
    int*   tidx = (int*)(tvals + 40960);     // 40960 ints
    float* hidden_h = (float*)(tidx + 40960);
    float* v2 = hidden_h + 524288;           // 4096
    float* hhn = v2 + 4096;                  // 4096
    float* hsi0 = hhn + 4096;                // 524288
    float* h_si = hsi0 + 524288;
    float* h_back = h_si + 524288;
    float* out_hs = h_back + 524288;
    float* indi = out_hs + 524288;
    float* out_indi = indi + 524288;
    // overlays inside BIG (dead before hs2c GEMM writes BIG):
    float* seqt = BIG;                       // 5,242,880  (GRU phase)
    float* gx0 = BIG + 5242880;              // 1,572,864
    float* gh0 = gx0 + 1572864;
    float* gx1 = gh0 + 1572864;
    float* gh1 = gx1 + 1572864;              // ends 11,534,336
    float* s2cT = BIG;                       // 2,097,152  (concept phase)
    float* L    = BIG + 2097152;             // 2,097,152  (logits^T -> softmax)
    float* c2s  = BIG + 4194304;             // 2,097,152

    // ================= Phase A: 2-layer GRU =================
    seq_transpose<<<(TSTEPS * NR * DDIM) / 256, 256, 0, stream>>>(x, seqt);
    hipMemsetAsync(h0, 0, 524288 * sizeof(float), stream);
    hipMemsetAsync(h1, 0, 524288 * sizeof(float), stream);
    for (int t = 0; t < TSTEPS; t++) {
        GemmArgs a{seqt + (size_t)t * NR * DDIM, wih0, nullptr, gx0, 384, DDIM, 1};
        GemmArgs b{h0, whh0, nullptr, gh0, 384, HDIM, 1};
        gemm_multi<<<dim3(6, 64, 2), 256, 0, stream>>>(a, b);
        gru_update<<<2048, 256, 0, stream>>>(h0, gx0, gh0, bih0, bhh0);
        GemmArgs c{h0, wih1, nullptr, gx1, 384, HDIM, 1};
        GemmArgs d{h1, whh1, nullptr, gh1, 384, HDIM, 1};
        gemm_multi<<<dim3(6, 64, 2), 256, 0, stream>>>(c, d);
        gru_update<<<2048, 256, 0, stream>>>(h1, gx1, gh1, bih1, bhh1);
    }
    float* x_hidden = h1;

    // ================= Phase B: predefined-concept branch =================
    den_kernel<<<8, 256, 0, stream>>>(cm, mv, den);
    s2ct_kernel<<<(CDIM * NR) / 256, 256, 0, stream>>>(cm, mv, den, s2cT);
    launch_gemm(stream, s2cT, x_hidden, nullptr, hidden, CDIM, HDIM, NR, 0);   // [512,128]
    row_nonzero<<<CDIM, 64, 0, stream>>>(hidden, v1);
    launch_gemm(stream, hidden, x_hidden, nullptr, L, CDIM, NR, HDIM, 1);      // L[c,n]
    cos_softmax_row<<<CDIM, 256, 0, stream>>>(L, NR, nullptr, nullptr, nullptr); // col-softmax
    launch_gemm(stream, L, x_hidden, nullptr, hidden2, CDIM, HDIM, NR, 0);     // [512,128]
    row_norm<<<NR, 64, 0, stream>>>(x_hidden, xnorm);
    row_norm<<<CDIM, 64, 0, stream>>>(hidden2, h2n);
    launch_gemm(stream, x_hidden, hidden2, nullptr, c2s, NR, CDIM, HDIM, 1);   // dots
    cos_softmax_row<<<NR, 256, 0, stream>>>(c2s, CDIM, xnorm, h2n, v1);
    launch_gemm(stream, c2s, hidden2, nullptr, p0, NR, HDIM, CDIM, 0);
    launch_gemm(stream, p0, w_ps, b_ps, p_shared, NR, HDIM, HDIM, 1 | 2);
    launch_gemm(stream, p_shared, w_ps_back, b_ps_back, p_back, NR, HDIM, HDIM, 1 | 2);
    launch_gemm(stream, p_shared, w_ps_fore, b_ps_fore, out_ps, NR, HDIM, HDIM, 1 | 2 | 4);

    // ================= Phase C: hidden-concept branch =================
    sub2_kernel<<<2048, 256, 0, stream>>>(x_hidden, p_back, h_shared);
    row_norm<<<NR, 64, 0, stream>>>(h_shared, hn);
    launch_gemm(stream, h_shared, h_shared, nullptr, BIG, NR, NR, HDIM, 1);    // hs2c dots
    hs2c_norm<<<(NR * NR) / 256, 256, 0, stream>>>(BIG, hn, diagv);
    topk_kernel<<<NR, 256, 0, stream>>>(BIG, tvals, tidx);
    hipMemsetAsync(colsum, 0, NR * sizeof(float), stream);
    hipMemsetAsync(hidden_h, 0, 524288 * sizeof(float), stream);
    colsum_scatter<<<(NR * KTOP + 255) / 256, 256, 0, stream>>>(tvals, tidx, colsum);
    hh_scatter<<<NR * KTOP, HDIM, 0, stream>>>(tvals, tidx, h_shared, hidden_h);
    hh_diag<<<2048, 256, 0, stream>>>(colsum, diagv, h_shared, hidden_h);
    row_nonzero<<<NR, 64, 0, stream>>>(hidden_h, v2);
    row_norm<<<NR, 64, 0, stream>>>(hidden_h, hhn);
    launch_gemm(stream, h_shared, hidden_h, nullptr, BIG, NR, NR, HDIM, 1);    // hc2s dots
    cos_softmax_row<<<NR, 256, 0, stream>>>(BIG, NR, hn, hhn, v2);
    launch_gemm(stream, BIG, hidden_h, nullptr, hsi0, NR, HDIM, NR, 0);
    launch_gemm(stream, hsi0, w_hs, b_hs, h_si, NR, HDIM, HDIM, 1 | 2);
    launch_gemm(stream, h_si, w_hs_back, b_hs_back, h_back, NR, HDIM, HDIM, 1 | 2);
    launch_gemm(stream, h_si, w_hs_fore, b_hs_fore, out_hs, NR, HDIM, HDIM, 1 | 2 | 4);

    // ================= Phase D: individual branch + head =================
    sub3_kernel<<<2048, 256, 0, stream>>>(x_hidden, p_back, h_back, indi);
    launch_gemm(stream, indi, w_indi, b_indi, out_indi, NR, HDIM, HDIM, 1 | 2 | 4);
    head_kernel<<<NR, 64, 0, stream>>>(out_ps, out_hs, out_indi, w_out, b_out, out);
}